// Round 22
// baseline (4369.519 us; speedup 1.0000x reference)
//
#include <hip/hip_runtime.h>
#include <hip/hip_bf16.h>

#define DD 128

// SOLVED CHANNEL MODEL (R8/R9/R17/R21 + npz-size evidence):
//   d_out is FLOAT32; comparator reads flat[i] = dev_f32[i], NO offset.
//   out_a = f32[Na*128], out_b = f32[Nb*128], rw = f32[3], concatenated.
// SEMANTICS (R17 anchor at (0,0), R18 in-situ 64-row verifier):
//   dict slots, straight f32 inputs, x C-order (N,128), W C-order (128,128),
//   rw = softmax(rel_logits), mean = seg_sum/max(cnt,1),
//   out_a = rw0*(mean0@Wl0+bl0+x_a@Wr0) + rw2*(mean2@Wl2+bl2+x_b->a terms)
//   out_b = rw1*(mean1@Wl1+bl1+x_b@Wr1)

// ---- prep: softmax + combined f32 weights ----
__global__ void prep_kernel(const float* __restrict__ Wl0, const float* __restrict__ bl0, const float* __restrict__ Wr0,
                            const float* __restrict__ Wl1, const float* __restrict__ bl1, const float* __restrict__ Wr1,
                            const float* __restrict__ Wl2, const float* __restrict__ bl2, const float* __restrict__ Wr2,
                            const float* __restrict__ rl,
                            float* __restrict__ WA, float* __restrict__ WB,
                            float* __restrict__ ba, float* __restrict__ bb,
                            float* __restrict__ rw_out) {
    const int n = threadIdx.x;  // 0..127
    float l0 = rl[0], l1 = rl[1], l2 = rl[2];
    float mx = fmaxf(l0, fmaxf(l1, l2));
    float e0 = expf(l0 - mx), e1 = expf(l1 - mx), e2 = expf(l2 - mx);
    float s = e0 + e1 + e2;
    float r0 = e0 / s, r1 = e1 / s, r2 = e2 / s;
    for (int k = 0; k < DD; k++) {
        WA[k * DD + n]         = r0 * Wl0[k * DD + n];
        WA[(128 + k) * DD + n] = r0 * Wr0[k * DD + n] + r2 * Wr2[k * DD + n];
        WA[(256 + k) * DD + n] = r2 * Wl2[k * DD + n];
        WB[k * DD + n]         = r1 * Wl1[k * DD + n];
        WB[(128 + k) * DD + n] = r1 * Wr1[k * DD + n];
    }
    ba[n] = r0 * bl0[n] + r2 * bl2[n];
    bb[n] = r1 * bl1[n];
    if (n < 3) rw_out[n] = (n == 0 ? r0 : (n == 1 ? r1 : r2));
}

__global__ __launch_bounds__(256) void count_kernel(const int* __restrict__ dst, float* __restrict__ cnt,
                                                    int E, int Nd) {
    int e = blockIdx.x * 256 + threadIdx.x;
    if (e >= E) return;
    int d = dst[e];
    if (d >= 0 && d < Nd) atomicAdd(cnt + d, 1.0f);
}

__global__ __launch_bounds__(256) void scatter_kernel(const float* __restrict__ x,
                                                      const int* __restrict__ src,
                                                      const int* __restrict__ dst,
                                                      float* __restrict__ agg,
                                                      int E, int rlo, int rhi, int Nsrc) {
    long long t = (long long)blockIdx.x * 256 + threadIdx.x;
    if (t >= (long long)E * 32) return;
    int e = (int)(t >> 5);
    int c = (int)(t & 31);
    int d = dst[e];
    if (d < rlo || d >= rhi) return;
    int si = src[e];
    if (si < 0 || si >= Nsrc) return;
    const float4 v = *(const float4*)(x + (size_t)si * DD + c * 4);
    float* a = agg + (size_t)(d - rlo) * DD + c * 4;
    atomicAdd(a + 0, v.x);
    atomicAdd(a + 1, v.y);
    atomicAdd(a + 2, v.z);
    atomicAdd(a + 3, v.w);
}

// ---- scalar out_a: out_f32[row*128+n] = ba[n] + sum_k sv[k]*WA[k][n] ----
__global__ __launch_bounds__(128) void gemm_a(const float* __restrict__ S0, const float* __restrict__ C0,
                                              const float* __restrict__ S2, const float* __restrict__ C2,
                                              const float* __restrict__ X,
                                              const float* __restrict__ WA, const float* __restrict__ ba,
                                              float* __restrict__ out, int rlo) {
    __shared__ float sv[384];
    const int n = threadIdx.x;
    const size_t lrow = blockIdx.x;
    const size_t row = (size_t)rlo + lrow;
    const float i0 = 1.0f / fmaxf(C0[row], 1.0f);
    const float i2 = 1.0f / fmaxf(C2[row], 1.0f);
    sv[n]       = S0[lrow * DD + n] * i0;
    sv[128 + n] = X[row * DD + n];
    sv[256 + n] = S2[lrow * DD + n] * i2;
    __syncthreads();
    float acc = ba[n];
    for (int k = 0; k < 384; k++) acc += sv[k] * WA[k * DD + n];
    out[row * DD + n] = acc;                               // FLOAT32 write
}

__global__ __launch_bounds__(128) void gemm_b(const float* __restrict__ S0, const float* __restrict__ C0,
                                              const float* __restrict__ X,
                                              const float* __restrict__ WB, const float* __restrict__ bb,
                                              float* __restrict__ out, int rlo) {
    __shared__ float sv[256];
    const int n = threadIdx.x;
    const size_t lrow = blockIdx.x;
    const size_t row = (size_t)rlo + lrow;
    const float i0 = 1.0f / fmaxf(C0[row], 1.0f);
    sv[n]       = S0[lrow * DD + n] * i0;
    sv[128 + n] = X[row * DD + n];
    __syncthreads();
    float acc = bb[n];
    for (int k = 0; k < 256; k++) acc += sv[k] * WB[k * DD + n];
    out[row * DD + n] = acc;                               // FLOAT32 write
}

static inline int imin(int a, int b) { return a < b ? a : b; }
static inline long long llmin(long long a, long long b) { return a < b ? a : b; }

extern "C" void kernel_launch(void* const* d_in, const int* in_sizes, int n_in,
                              void* d_out, int out_size, void* d_ws, size_t ws_size,
                              hipStream_t stream) {
    if (n_in != 18) return;

    const float* x_a = (const float*)d_in[0];
    const float* x_b = (const float*)d_in[1];
    const int* e0_src = (const int*)d_in[2];
    const int* e0_dst = (const int*)d_in[3];
    const int* e1_src = (const int*)d_in[4];
    const int* e1_dst = (const int*)d_in[5];
    const int* e2_src = (const int*)d_in[6];
    const int* e2_dst = (const int*)d_in[7];
    const float* Wl0 = (const float*)d_in[8];
    const float* bl0 = (const float*)d_in[9];
    const float* Wr0 = (const float*)d_in[10];
    const float* Wl1 = (const float*)d_in[11];
    const float* bl1 = (const float*)d_in[12];
    const float* Wr1 = (const float*)d_in[13];
    const float* Wl2 = (const float*)d_in[14];
    const float* bl2 = (const float*)d_in[15];
    const float* Wr2 = (const float*)d_in[16];
    const float* rl  = (const float*)d_in[17];

    const int Na = in_sizes[0] / DD;   // 200000
    const int Nb = in_sizes[1] / DD;   // 100000
    const int E0 = in_sizes[2], E1 = in_sizes[4], E2 = in_sizes[6];

    // FLOAT32 outputs, natural indexing, no offset
    float* out_f = (float*)d_out;
    float* out_a = out_f;
    float* out_b = out_f + (size_t)Na * DD;
    float* rw_out = out_f + (size_t)Na * DD + (size_t)Nb * DD;

    char* base = (char*)d_ws;
    size_t off = 0;
    auto alloc = [&](size_t bytes) { char* r = base + off; off += (bytes + 511) & ~(size_t)511; return r; };
    float* cnt0 = (float*)alloc((size_t)Na * 4);
    float* cnt1 = (float*)alloc((size_t)Nb * 4);
    float* cnt2 = (float*)alloc((size_t)Na * 4);
    size_t cnt_region = off;
    float* WA = (float*)alloc(384 * DD * 4);
    float* WB = (float*)alloc(256 * DD * 4);
    float* ba = (float*)alloc(512);
    float* bb = (float*)alloc(512);
    size_t fixed = off;
    float* aggBase = (float*)(base + fixed);
    if (ws_size < fixed + (1u << 20)) return;

    const size_t aggBytes = ws_size - fixed;
    const long long rowsTotal = (long long)(aggBytes / (DD * 4));
    int capB = (int)llmin((long long)Nb, (rowsTotal / 16) * 16);
    int capA = (int)llmin((long long)Na, ((rowsTotal / 2) / 16) * 16);
    if (capB < 16) capB = 16;
    if (capA < 16) capA = 16;

    hipMemsetAsync(d_ws, 0, cnt_region, stream);
    prep_kernel<<<1, 128, 0, stream>>>(Wl0, bl0, Wr0, Wl1, bl1, Wr1, Wl2, bl2, Wr2, rl,
                                       WA, WB, ba, bb, rw_out);
    count_kernel<<<(E0 + 255) / 256, 256, 0, stream>>>(e0_dst, cnt0, E0, Na);
    count_kernel<<<(E1 + 255) / 256, 256, 0, stream>>>(e1_dst, cnt1, E1, Nb);
    count_kernel<<<(E2 + 255) / 256, 256, 0, stream>>>(e2_dst, cnt2, E2, Na);

    const int sc0 = (int)(((long long)E0 * 32 + 255) / 256);
    const int sc1 = (int)(((long long)E1 * 32 + 255) / 256);
    const int sc2 = (int)(((long long)E2 * 32 + 255) / 256);

    // relation 1 (a -> b) -> out_b
    for (int r0 = 0; r0 < Nb; r0 += capB) {
        const int r1 = imin(Nb, r0 + capB);
        const int rows = r1 - r0;
        hipMemsetAsync(aggBase, 0, (size_t)rows * DD * 4, stream);
        scatter_kernel<<<sc1, 256, 0, stream>>>(x_a, e1_src, e1_dst, aggBase, E1, r0, r1, Na);
        gemm_b<<<rows, 128, 0, stream>>>(aggBase, cnt1, x_b, WB, bb, out_b, r0);
    }

    // relations 0 (a->a) + 2 (b->a) -> out_a
    float* agg0 = aggBase;
    float* agg2 = aggBase + (size_t)capA * DD;
    for (int r0 = 0; r0 < Na; r0 += capA) {
        const int r1 = imin(Na, r0 + capA);
        const int rows = r1 - r0;
        hipMemsetAsync(agg0, 0, (size_t)rows * DD * 4, stream);
        hipMemsetAsync(agg2, 0, (size_t)rows * DD * 4, stream);
        scatter_kernel<<<sc0, 256, 0, stream>>>(x_a, e0_src, e0_dst, agg0, E0, r0, r1, Na);
        scatter_kernel<<<sc2, 256, 0, stream>>>(x_b, e2_src, e2_dst, agg2, E2, r0, r1, Nb);
        gemm_a<<<rows, 128, 0, stream>>>(agg0, cnt0, agg2, cnt2, x_a, WA, ba, out_a, r0);
    }
}

// Round 23
// 2934.645 us; speedup vs baseline: 1.4889x; 1.4889x over previous
//
#include <hip/hip_runtime.h>
#include <hip/hip_bf16.h>

#define DD 128

typedef float f32x4 __attribute__((ext_vector_type(4)));
typedef __bf16 bf16x8 __attribute__((ext_vector_type(8)));

// CHANNEL MODEL (R22, verified PASS): d_out is FLOAT32, flat[i] = dev_f32[i].
// SEMANTICS verified R17/R18/R22. This round: MFMA bf16 GEMM + in-place agg
// (agg0 -> out_a region, agg1 -> out_b region, agg2 -> ws chunked).

// ---- prep: softmax + premultiplied bf16 W^T tables [outcol][k] ----
// WtA [128][384]: k<128: r0*Wl0(k,n) | +128: r0*Wr0+r2*Wr2 | +256: r2*Wl2
// Wtb [128][256]: k<128: r1*Wl1(k,n) | +128: r1*Wr1
__global__ void prep_kernel(const float* __restrict__ Wl0, const float* __restrict__ bl0, const float* __restrict__ Wr0,
                            const float* __restrict__ Wl1, const float* __restrict__ bl1, const float* __restrict__ Wr1,
                            const float* __restrict__ Wl2, const float* __restrict__ bl2, const float* __restrict__ Wr2,
                            const float* __restrict__ rl,
                            __bf16* __restrict__ WtA, __bf16* __restrict__ Wtb,
                            float* __restrict__ ba, float* __restrict__ bb,
                            float* __restrict__ rw_out) {
    const int n = threadIdx.x;  // 0..127 output column
    float l0 = rl[0], l1 = rl[1], l2 = rl[2];
    float mx = fmaxf(l0, fmaxf(l1, l2));
    float e0 = expf(l0 - mx), e1 = expf(l1 - mx), e2 = expf(l2 - mx);
    float s = e0 + e1 + e2;
    float r0 = e0 / s, r1 = e1 / s, r2 = e2 / s;

    for (int k = 0; k < DD; k++) {
        WtA[n * 384 + k]       = (__bf16)(r0 * Wl0[k * DD + n]);
        WtA[n * 384 + 128 + k] = (__bf16)(r0 * Wr0[k * DD + n] + r2 * Wr2[k * DD + n]);
        WtA[n * 384 + 256 + k] = (__bf16)(r2 * Wl2[k * DD + n]);
        Wtb[n * 256 + k]       = (__bf16)(r1 * Wl1[k * DD + n]);
        Wtb[n * 256 + 128 + k] = (__bf16)(r1 * Wr1[k * DD + n]);
    }
    ba[n] = r0 * bl0[n] + r2 * bl2[n];
    bb[n] = r1 * bl1[n];
    if (n < 3) rw_out[n] = (n == 0 ? r0 : (n == 1 ? r1 : r2));
}

__global__ __launch_bounds__(256) void count_kernel(const int* __restrict__ dst, float* __restrict__ cnt,
                                                    int E, int Nd) {
    int e = blockIdx.x * 256 + threadIdx.x;
    if (e >= E) return;
    int d = dst[e];
    if (d >= 0 && d < Nd) atomicAdd(cnt + d, 1.0f);
}

__global__ __launch_bounds__(256) void scatter_kernel(const float* __restrict__ x,
                                                      const int* __restrict__ src,
                                                      const int* __restrict__ dst,
                                                      float* __restrict__ agg,
                                                      int E, int rlo, int rhi, int Nsrc) {
    long long t = (long long)blockIdx.x * 256 + threadIdx.x;
    if (t >= (long long)E * 32) return;
    int e = (int)(t >> 5);
    int c = (int)(t & 31);
    int d = dst[e];
    if (d < rlo || d >= rhi) return;
    int si = src[e];
    if (si < 0 || si >= Nsrc) return;
    const float4 v = *(const float4*)(x + (size_t)si * DD + c * 4);
    float* a = agg + (size_t)(d - rlo) * DD + c * 4;
    atomicAdd(a + 0, v.x);
    atomicAdd(a + 1, v.y);
    atomicAdd(a + 2, v.z);
    atomicAdd(a + 3, v.w);
}

// ---- fused MFMA GEMM over rows [rlo, rlo+16*nTiles), f32 out in-place over S0 ----
// KSRC=3: out = S0/max(C0,1) @ WtA + X @ WtA[128:] + S2/max(C2,1) @ WtA[256:] + ba  (K=384)
// KSRC=2: out = S0/max(C0,1) @ Wtb + X @ Wtb[128:] + bb                              (K=256)
// S0 GLOBAL rows (aliases out!), S2 chunk-local rows, X global rows.
// B-fragments read directly from global (W tables are L2-resident, ~100KB).
template <int KSRC>
__global__ __launch_bounds__(256) void fused_gemm(const float* S0, const float* __restrict__ C0,
                                                  const float* __restrict__ S2, const float* __restrict__ C2,
                                                  const float* __restrict__ X,
                                                  const __bf16* __restrict__ Wt,
                                                  const float* __restrict__ bias,
                                                  float* out, int rlo, int nTiles) {
    constexpr int K = KSRC * 128;
    const int lane = threadIdx.x & 63;
    const int m = lane & 15;        // A row in tile / C-D col
    const int g = lane >> 4;        // k-group / C-D row group
    const int wave = (blockIdx.x * 256 + threadIdx.x) >> 6;
    const int nWaves = gridDim.x * 4;

    for (int t = wave; t < nTiles; t += nWaves) {
        const size_t row = (size_t)rlo + t * 16 + m;      // this lane's A row
        const float s0 = 1.0f / fmaxf(C0[row], 1.0f);
        float s2 = 0.f;
        if (KSRC == 3) s2 = 1.0f / fmaxf(C2[row], 1.0f);

        f32x4 acc[8];
#pragma unroll
        for (int n = 0; n < 8; n++) acc[n] = (f32x4)0.0f;

#pragma unroll
        for (int ks = 0; ks < K / 32; ks++) {
            const int koff = ks * 32 + g * 8;
            const float* ap;
            float scale;
            if (koff < 128)                   { ap = S0 + row * DD + koff;                          scale = s0;  }
            else if (KSRC == 2 || koff < 256) { ap = X  + row * DD + (koff - 128);                  scale = 1.f; }
            else                              { ap = S2 + (row - rlo) * DD + (koff - 256);          scale = s2;  }
            const float4 v0 = ((const float4*)ap)[0];
            const float4 v1 = ((const float4*)ap)[1];
            bf16x8 a;
            a[0] = (__bf16)(v0.x * scale);
            a[1] = (__bf16)(v0.y * scale);
            a[2] = (__bf16)(v0.z * scale);
            a[3] = (__bf16)(v0.w * scale);
            a[4] = (__bf16)(v1.x * scale);
            a[5] = (__bf16)(v1.y * scale);
            a[6] = (__bf16)(v1.z * scale);
            a[7] = (__bf16)(v1.w * scale);
#pragma unroll
            for (int n = 0; n < 8; n++) {
                const bf16x8 b = *(const bf16x8*)(Wt + (size_t)(n * 16 + m) * K + koff);
                acc[n] = __builtin_amdgcn_mfma_f32_16x16x32_bf16(a, b, acc[n], 0, 0, 0);
            }
        }

#pragma unroll
        for (int n = 0; n < 8; n++) {
            const int col = n * 16 + m;
            const float bv = bias[col];
#pragma unroll
            for (int r = 0; r < 4; r++) {
                const size_t orow = (size_t)rlo + t * 16 + g * 4 + r;
                out[orow * DD + col] = acc[n][r] + bv;    // f32 store (in-place over S0)
            }
        }
    }
}

static inline int imin(int a, int b) { return a < b ? a : b; }
static inline long long llmin(long long a, long long b) { return a < b ? a : b; }

extern "C" void kernel_launch(void* const* d_in, const int* in_sizes, int n_in,
                              void* d_out, int out_size, void* d_ws, size_t ws_size,
                              hipStream_t stream) {
    if (n_in != 18) return;

    const float* x_a = (const float*)d_in[0];
    const float* x_b = (const float*)d_in[1];
    const int* e0_src = (const int*)d_in[2];
    const int* e0_dst = (const int*)d_in[3];
    const int* e1_src = (const int*)d_in[4];
    const int* e1_dst = (const int*)d_in[5];
    const int* e2_src = (const int*)d_in[6];
    const int* e2_dst = (const int*)d_in[7];
    const float* Wl0 = (const float*)d_in[8];
    const float* bl0 = (const float*)d_in[9];
    const float* Wr0 = (const float*)d_in[10];
    const float* Wl1 = (const float*)d_in[11];
    const float* bl1 = (const float*)d_in[12];
    const float* Wr1 = (const float*)d_in[13];
    const float* Wl2 = (const float*)d_in[14];
    const float* bl2 = (const float*)d_in[15];
    const float* Wr2 = (const float*)d_in[16];
    const float* rl  = (const float*)d_in[17];

    const int Na = in_sizes[0] / DD;   // 200000
    const int Nb = in_sizes[1] / DD;   // 100000
    const int E0 = in_sizes[2], E1 = in_sizes[4], E2 = in_sizes[6];

    float* out_f = (float*)d_out;
    float* out_a = out_f;                                   // also agg0 (in-place)
    float* out_b = out_f + (size_t)Na * DD;                 // also agg1 (in-place)
    float* rw_out = out_f + (size_t)Na * DD + (size_t)Nb * DD;

    char* base = (char*)d_ws;
    size_t off = 0;
    auto alloc = [&](size_t bytes) { char* r = base + off; off += (bytes + 511) & ~(size_t)511; return r; };
    float* cnt0 = (float*)alloc((size_t)Na * 4);
    float* cnt1 = (float*)alloc((size_t)Nb * 4);
    float* cnt2 = (float*)alloc((size_t)Na * 4);
    size_t cnt_region = off;
    __bf16* WtA = (__bf16*)alloc(128 * 384 * 2);
    __bf16* Wtb = (__bf16*)alloc(128 * 256 * 2);
    float* ba = (float*)alloc(512);
    float* bb = (float*)alloc(512);
    size_t fixed = off;
    float* agg2Base = (float*)(base + fixed);
    if (ws_size < fixed + (1u << 20)) return;

    const size_t aggBytes = ws_size - fixed;
    int capA = (int)llmin((long long)Na, ((long long)(aggBytes / (DD * 4)) / 16) * 16);
    if (capA < 16) capA = 16;

    // zero: counts + agg regions (out_a, out_b used as f32 accumulators)
    hipMemsetAsync(d_ws, 0, cnt_region, stream);
    hipMemsetAsync(out_a, 0, (size_t)Na * DD * 4, stream);
    hipMemsetAsync(out_b, 0, (size_t)Nb * DD * 4, stream);

    prep_kernel<<<1, 128, 0, stream>>>(Wl0, bl0, Wr0, Wl1, bl1, Wr1, Wl2, bl2, Wr2, rl,
                                       WtA, Wtb, ba, bb, rw_out);
    count_kernel<<<(E0 + 255) / 256, 256, 0, stream>>>(e0_dst, cnt0, E0, Na);
    count_kernel<<<(E1 + 255) / 256, 256, 0, stream>>>(e1_dst, cnt1, E1, Nb);
    count_kernel<<<(E2 + 255) / 256, 256, 0, stream>>>(e2_dst, cnt2, E2, Na);

    const int sc0 = (int)(((long long)E0 * 32 + 255) / 256);
    const int sc1 = (int)(((long long)E1 * 32 + 255) / 256);
    const int sc2 = (int)(((long long)E2 * 32 + 255) / 256);

    // full-range scatters into output regions (agg0, agg1) — edges scanned ONCE
    scatter_kernel<<<sc0, 256, 0, stream>>>(x_a, e0_src, e0_dst, out_a, E0, 0, Na, Na);
    scatter_kernel<<<sc1, 256, 0, stream>>>(x_a, e1_src, e1_dst, out_b, E1, 0, Nb, Na);

    // out_b: K=256 MFMA GEMM, in-place over agg1
    {
        const int nT = Nb / 16;
        const int blocks = imin(1024, (nT + 3) / 4);
        fused_gemm<2><<<blocks, 256, 0, stream>>>(out_b, cnt1, nullptr, nullptr, x_b, Wtb, bb, out_b, 0, nT);
    }

    // out_a: agg2 chunked in ws; K=384 MFMA GEMM, in-place over agg0
    for (int r0 = 0; r0 < Na; r0 += capA) {
        const int r1 = imin(Na, r0 + capA);
        const int rows = r1 - r0;
        hipMemsetAsync(agg2Base, 0, (size_t)rows * DD * 4, stream);
        scatter_kernel<<<sc2, 256, 0, stream>>>(x_b, e2_src, e2_dst, agg2Base, E2, r0, r1, Nb);
        const int nT = rows / 16;
        const int blocks = imin(1024, (nT + 3) / 4);
        fused_gemm<3><<<blocks, 256, 0, stream>>>(out_a, cnt0, agg2Base, cnt2, x_a, WtA, ba, out_a, r0, nT);
    }
}

// Round 24
// 641.801 us; speedup vs baseline: 6.8082x; 4.5725x over previous
//
#include <hip/hip_runtime.h>
#include <hip/hip_bf16.h>

#define DD 128
#define CAP 32
#define OVF_CAP 8192

typedef float f32x4 __attribute__((ext_vector_type(4)));
typedef __bf16 bf16x8 __attribute__((ext_vector_type(8)));

// ---- prep: softmax + premultiplied bf16 W^T tables [outcol][k] ----
__global__ void prep_kernel(const float* __restrict__ Wl0, const float* __restrict__ bl0, const float* __restrict__ Wr0,
                            const float* __restrict__ Wl1, const float* __restrict__ bl1, const float* __restrict__ Wr1,
                            const float* __restrict__ Wl2, const float* __restrict__ bl2, const float* __restrict__ Wr2,
                            const float* __restrict__ rl,
                            __bf16* __restrict__ WtA, __bf16* __restrict__ Wtb,
                            float* __restrict__ ba, float* __restrict__ bb,
                            float* __restrict__ rw_out) {
    const int n = threadIdx.x;
    float l0 = rl[0], l1 = rl[1], l2 = rl[2];
    float mx = fmaxf(l0, fmaxf(l1, l2));
    float e0 = expf(l0 - mx), e1 = expf(l1 - mx), e2 = expf(l2 - mx);
    float s = e0 + e1 + e2;
    float r0 = e0 / s, r1 = e1 / s, r2 = e2 / s;
    for (int k = 0; k < DD; k++) {
        WtA[n * 384 + k]       = (__bf16)(r0 * Wl0[k * DD + n]);
        WtA[n * 384 + 128 + k] = (__bf16)(r0 * Wr0[k * DD + n] + r2 * Wr2[k * DD + n]);
        WtA[n * 384 + 256 + k] = (__bf16)(r2 * Wl2[k * DD + n]);
        Wtb[n * 256 + k]       = (__bf16)(r1 * Wl1[k * DD + n]);
        Wtb[n * 256 + 128 + k] = (__bf16)(r1 * Wr1[k * DD + n]);
    }
    ba[n] = r0 * bl0[n] + r2 * bl2[n];
    bb[n] = r1 * bl1[n];
    if (n < 3) rw_out[n] = (n == 0 ? r0 : (n == 1 ? r1 : r2));
}

// ---- fill: bucket[d][slot]=src, cnt[d]=true degree; overflow -> list ----
__global__ __launch_bounds__(256) void fill_bucket(const int* __restrict__ src, const int* __restrict__ dst,
                                                   int E, int Nd, int Ns,
                                                   int* __restrict__ cnt, int* __restrict__ bucket,
                                                   int* __restrict__ ovf_cnt, int2* __restrict__ ovf) {
    int e = blockIdx.x * 256 + threadIdx.x;
    if (e >= E) return;
    int d = dst[e];
    if (d < 0 || d >= Nd) return;
    int s = src[e];
    if (s < 0 || s >= Ns) return;
    int slot = atomicAdd(&cnt[d], 1);
    if (slot < CAP) bucket[(size_t)d * CAP + slot] = s;
    else { int o = atomicAdd(ovf_cnt, 1); if (o < OVF_CAP) ovf[o] = make_int2(d, s); }
}

// ---- gather: agg[lrow][n] = sum over bucket sources (no atomics) ----
__global__ __launch_bounds__(128) void gather_sum(const float* __restrict__ x,
                                                  const int* __restrict__ cnt,
                                                  const int* __restrict__ bucket,
                                                  float* __restrict__ agg, int rlo, int rows) {
    const int lrow = blockIdx.x;
    if (lrow >= rows) return;
    const int row = rlo + lrow;
    const int n = threadIdx.x;
    int deg = cnt[row];
    if (deg > CAP) deg = CAP;
    const int* bk = bucket + (size_t)row * CAP;
    float s = 0.f;
    for (int i = 0; i < deg; i++) s += x[(size_t)bk[i] * DD + n];
    agg[(size_t)lrow * DD + n] = s;
}

// ---- overflow fixup (rare; atomic, after gather) ----
__global__ __launch_bounds__(128) void ovf_apply(const int* __restrict__ ovf_cnt, const int2* __restrict__ ovf,
                                                 const float* __restrict__ x,
                                                 float* __restrict__ agg, int rlo, int rhi) {
    int m = *ovf_cnt;
    if (m > OVF_CAP) m = OVF_CAP;
    for (int i = blockIdx.x; i < m; i += gridDim.x) {
        int2 p = ovf[i];
        if (p.x < rlo || p.x >= rhi) continue;
        atomicAdd(&agg[(size_t)(p.x - rlo) * DD + threadIdx.x], x[(size_t)p.y * DD + threadIdx.x]);
    }
}

// ---- atomic-scatter fallback (small-ws path; R23-verified) ----
__global__ __launch_bounds__(256) void scatter_kernel(const float* __restrict__ x,
                                                      const int* __restrict__ src,
                                                      const int* __restrict__ dst,
                                                      float* __restrict__ agg,
                                                      int E, int rlo, int rhi, int Nsrc) {
    long long t = (long long)blockIdx.x * 256 + threadIdx.x;
    if (t >= (long long)E * 32) return;
    int e = (int)(t >> 5);
    int c = (int)(t & 31);
    int d = dst[e];
    if (d < rlo || d >= rhi) return;
    int si = src[e];
    if (si < 0 || si >= Nsrc) return;
    const float4 v = *(const float4*)(x + (size_t)si * DD + c * 4);
    float* a = agg + (size_t)(d - rlo) * DD + c * 4;
    atomicAdd(a + 0, v.x);
    atomicAdd(a + 1, v.y);
    atomicAdd(a + 2, v.z);
    atomicAdd(a + 3, v.w);
}
__global__ __launch_bounds__(256) void count_kernel(const int* __restrict__ dst, int* __restrict__ cnt,
                                                    int E, int Nd) {
    int e = blockIdx.x * 256 + threadIdx.x;
    if (e >= E) return;
    int d = dst[e];
    if (d >= 0 && d < Nd) atomicAdd(&cnt[d], 1);
}

// ---- fused MFMA GEMM (R23-verified), counts as int ----
template <int KSRC>
__global__ __launch_bounds__(256) void fused_gemm(const float* S0, const int* __restrict__ C0,
                                                  const float* __restrict__ S2, const int* __restrict__ C2,
                                                  const float* __restrict__ X,
                                                  const __bf16* __restrict__ Wt,
                                                  const float* __restrict__ bias,
                                                  float* out, int rlo, int nTiles) {
    constexpr int K = KSRC * 128;
    const int lane = threadIdx.x & 63;
    const int m = lane & 15;
    const int g = lane >> 4;
    const int wave = (blockIdx.x * 256 + threadIdx.x) >> 6;
    const int nWaves = gridDim.x * 4;

    for (int t = wave; t < nTiles; t += nWaves) {
        const size_t row = (size_t)rlo + t * 16 + m;
        const float s0 = 1.0f / fmaxf((float)C0[row], 1.0f);
        float s2 = 0.f;
        if (KSRC == 3) s2 = 1.0f / fmaxf((float)C2[row], 1.0f);

        f32x4 acc[8];
#pragma unroll
        for (int n = 0; n < 8; n++) acc[n] = (f32x4)0.0f;

#pragma unroll
        for (int ks = 0; ks < K / 32; ks++) {
            const int koff = ks * 32 + g * 8;
            const float* ap;
            float scale;
            if (koff < 128)                   { ap = S0 + row * DD + koff;                 scale = s0;  }
            else if (KSRC == 2 || koff < 256) { ap = X  + row * DD + (koff - 128);         scale = 1.f; }
            else                              { ap = S2 + (row - rlo) * DD + (koff - 256); scale = s2;  }
            const float4 v0 = ((const float4*)ap)[0];
            const float4 v1 = ((const float4*)ap)[1];
            bf16x8 a;
            a[0] = (__bf16)(v0.x * scale);
            a[1] = (__bf16)(v0.y * scale);
            a[2] = (__bf16)(v0.z * scale);
            a[3] = (__bf16)(v0.w * scale);
            a[4] = (__bf16)(v1.x * scale);
            a[5] = (__bf16)(v1.y * scale);
            a[6] = (__bf16)(v1.z * scale);
            a[7] = (__bf16)(v1.w * scale);
#pragma unroll
            for (int n = 0; n < 8; n++) {
                const bf16x8 b = *(const bf16x8*)(Wt + (size_t)(n * 16 + m) * K + koff);
                acc[n] = __builtin_amdgcn_mfma_f32_16x16x32_bf16(a, b, acc[n], 0, 0, 0);
            }
        }

#pragma unroll
        for (int n = 0; n < 8; n++) {
            const int col = n * 16 + m;
            const float bv = bias[col];
#pragma unroll
            for (int r = 0; r < 4; r++) {
                const size_t orow = (size_t)rlo + t * 16 + g * 4 + r;
                out[orow * DD + col] = acc[n][r] + bv;
            }
        }
    }
}

static inline int imin(int a, int b) { return a < b ? a : b; }
static inline long long llmin(long long a, long long b) { return a < b ? a : b; }

extern "C" void kernel_launch(void* const* d_in, const int* in_sizes, int n_in,
                              void* d_out, int out_size, void* d_ws, size_t ws_size,
                              hipStream_t stream) {
    if (n_in != 18) return;

    const float* x_a = (const float*)d_in[0];
    const float* x_b = (const float*)d_in[1];
    const int* e0_src = (const int*)d_in[2];
    const int* e0_dst = (const int*)d_in[3];
    const int* e1_src = (const int*)d_in[4];
    const int* e1_dst = (const int*)d_in[5];
    const int* e2_src = (const int*)d_in[6];
    const int* e2_dst = (const int*)d_in[7];
    const float* Wl0 = (const float*)d_in[8];
    const float* bl0 = (const float*)d_in[9];
    const float* Wr0 = (const float*)d_in[10];
    const float* Wl1 = (const float*)d_in[11];
    const float* bl1 = (const float*)d_in[12];
    const float* Wr1 = (const float*)d_in[13];
    const float* Wl2 = (const float*)d_in[14];
    const float* bl2 = (const float*)d_in[15];
    const float* Wr2 = (const float*)d_in[16];
    const float* rl  = (const float*)d_in[17];

    const int Na = in_sizes[0] / DD;   // 200000
    const int Nb = in_sizes[1] / DD;   // 100000
    const int E0 = in_sizes[2], E1 = in_sizes[4], E2 = in_sizes[6];

    float* out_f = (float*)d_out;
    float* out_a = out_f;                       // agg0 in-place
    float* out_b = out_f + (size_t)Na * DD;     // agg1 in-place
    float* rw_out = out_f + (size_t)Na * DD + (size_t)Nb * DD;

    char* base = (char*)d_ws;
    size_t off = 0;
    auto alloc = [&](size_t bytes) { char* r = base + off; off += (bytes + 511) & ~(size_t)511; return r; };
    int* cnt0 = (int*)alloc((size_t)Na * 4);
    int* cnt1 = (int*)alloc((size_t)Nb * 4);
    int* cnt2 = (int*)alloc((size_t)Na * 4);
    int* ovfc = (int*)alloc(512);                      // 3 counters
    int2* ovfl = (int2*)alloc(OVF_CAP * sizeof(int2));
    size_t zero_hi = off;                              // zero [0, zero_hi)
    __bf16* WtA = (__bf16*)alloc(128 * 384 * 2);
    __bf16* Wtb = (__bf16*)alloc(128 * 256 * 2);
    float* ba = (float*)alloc(512);
    float* bb = (float*)alloc(512);
    size_t fixed = off;
    const size_t bucketBytes = (size_t)Na * CAP * 4;   // 25.6 MB (Na >= Nb)
    int* bucket = (int*)alloc(bucketBytes);
    size_t after_bucket = off;
    float* agg2Base = (float*)(base + after_bucket);

    const bool bigws = (ws_size >= after_bucket + (1u << 20));
    if (!bigws && ws_size < fixed + (1u << 20)) return;

    hipMemsetAsync(d_ws, 0, zero_hi, stream);
    prep_kernel<<<1, 128, 0, stream>>>(Wl0, bl0, Wr0, Wl1, bl1, Wr1, Wl2, bl2, Wr2, rl,
                                       WtA, Wtb, ba, bb, rw_out);

    const int fb0 = (E0 + 255) / 256, fb1 = (E1 + 255) / 256, fb2 = (E2 + 255) / 256;

    if (bigws) {
        const size_t aggBytes = ws_size - after_bucket;
        int capA = (int)llmin((long long)Na, ((long long)(aggBytes / (DD * 4)) / 16) * 16);
        if (capA < 16) capA = 16;

        // relation 1 (a->b) -> out_b
        fill_bucket<<<fb1, 256, 0, stream>>>(e1_src, e1_dst, E1, Nb, Na, cnt1, bucket, ovfc + 1, ovfl);
        gather_sum<<<Nb, 128, 0, stream>>>(x_a, cnt1, bucket, out_b, 0, Nb);
        ovf_apply<<<64, 128, 0, stream>>>(ovfc + 1, ovfl, x_a, out_b, 0, Nb);
        fused_gemm<2><<<1024, 256, 0, stream>>>(out_b, cnt1, nullptr, nullptr, x_b, Wtb, bb, out_b, 0, Nb / 16);

        // relation 0 (a->a) -> agg0 (= out_a)
        fill_bucket<<<fb0, 256, 0, stream>>>(e0_src, e0_dst, E0, Na, Na, cnt0, bucket, ovfc + 0, ovfl);
        gather_sum<<<Na, 128, 0, stream>>>(x_a, cnt0, bucket, out_a, 0, Na);
        ovf_apply<<<64, 128, 0, stream>>>(ovfc + 0, ovfl, x_a, out_a, 0, Na);

        // relation 2 (b->a): fill once, gather+gemm chunked
        fill_bucket<<<fb2, 256, 0, stream>>>(e2_src, e2_dst, E2, Na, Nb, cnt2, bucket, ovfc + 2, ovfl);
        for (int r0 = 0; r0 < Na; r0 += capA) {
            const int r1 = imin(Na, r0 + capA);
            const int rows = r1 - r0;
            gather_sum<<<rows, 128, 0, stream>>>(x_b, cnt2, bucket, agg2Base, r0, rows);
            ovf_apply<<<64, 128, 0, stream>>>(ovfc + 2, ovfl, x_b, agg2Base, r0, r1);
            fused_gemm<3><<<1024, 256, 0, stream>>>(out_a, cnt0, agg2Base, cnt2, x_a, WtA, ba, out_a, r0, rows / 16);
        }
    } else {
        // fallback: atomic scatter (R23 structure)
        float* aggF = (float*)(base + fixed);
        const size_t aggBytes = ws_size - fixed;
        int capA = (int)llmin((long long)Na, ((long long)(aggBytes / (DD * 4)) / 16) * 16);
        if (capA < 16) capA = 16;
        hipMemsetAsync(out_a, 0, (size_t)Na * DD * 4, stream);
        hipMemsetAsync(out_b, 0, (size_t)Nb * DD * 4, stream);
        count_kernel<<<fb0, 256, 0, stream>>>(e0_dst, cnt0, E0, Na);
        count_kernel<<<fb1, 256, 0, stream>>>(e1_dst, cnt1, E1, Nb);
        count_kernel<<<fb2, 256, 0, stream>>>(e2_dst, cnt2, E2, Na);
        const int sc0 = (int)(((long long)E0 * 32 + 255) / 256);
        const int sc1 = (int)(((long long)E1 * 32 + 255) / 256);
        const int sc2 = (int)(((long long)E2 * 32 + 255) / 256);
        scatter_kernel<<<sc0, 256, 0, stream>>>(x_a, e0_src, e0_dst, out_a, E0, 0, Na, Na);
        scatter_kernel<<<sc1, 256, 0, stream>>>(x_a, e1_src, e1_dst, out_b, E1, 0, Nb, Na);
        fused_gemm<2><<<1024, 256, 0, stream>>>(out_b, cnt1, nullptr, nullptr, x_b, Wtb, bb, out_b, 0, Nb / 16);
        for (int r0 = 0; r0 < Na; r0 += capA) {
            const int r1 = imin(Na, r0 + capA);
            const int rows = r1 - r0;
            hipMemsetAsync(aggF, 0, (size_t)rows * DD * 4, stream);
            scatter_kernel<<<sc2, 256, 0, stream>>>(x_b, e2_src, e2_dst, aggF, E2, r0, r1, Nb);
            fused_gemm<3><<<1024, 256, 0, stream>>>(out_a, cnt0, aggF, cnt2, x_a, WtA, ba, out_a, r0, rows / 16);
        }
    }
}

// Round 25
// 608.998 us; speedup vs baseline: 7.1749x; 1.0539x over previous
//
#include <hip/hip_runtime.h>
#include <hip/hip_bf16.h>

#define DD 128
#define CAP02 16
#define CAP1 32
#define OVFC 4096

typedef float f32x4 __attribute__((ext_vector_type(4)));
typedef __bf16 bf16x8 __attribute__((ext_vector_type(8)));

// ---- prep: softmax + premultiplied bf16 W^T tables [outcol][k] ----
__global__ void prep_kernel(const float* __restrict__ Wl0, const float* __restrict__ bl0, const float* __restrict__ Wr0,
                            const float* __restrict__ Wl1, const float* __restrict__ bl1, const float* __restrict__ Wr1,
                            const float* __restrict__ Wl2, const float* __restrict__ bl2, const float* __restrict__ Wr2,
                            const float* __restrict__ rl,
                            __bf16* __restrict__ WtA, __bf16* __restrict__ Wtb,
                            float* __restrict__ ba, float* __restrict__ bb,
                            float* __restrict__ rw_out) {
    const int n = threadIdx.x;
    float l0 = rl[0], l1 = rl[1], l2 = rl[2];
    float mx = fmaxf(l0, fmaxf(l1, l2));
    float e0 = expf(l0 - mx), e1 = expf(l1 - mx), e2 = expf(l2 - mx);
    float s = e0 + e1 + e2;
    float r0 = e0 / s, r1 = e1 / s, r2 = e2 / s;
    for (int k = 0; k < DD; k++) {
        WtA[n * 384 + k]       = (__bf16)(r0 * Wl0[k * DD + n]);
        WtA[n * 384 + 128 + k] = (__bf16)(r0 * Wr0[k * DD + n] + r2 * Wr2[k * DD + n]);
        WtA[n * 384 + 256 + k] = (__bf16)(r2 * Wl2[k * DD + n]);
        Wtb[n * 256 + k]       = (__bf16)(r1 * Wl1[k * DD + n]);
        Wtb[n * 256 + 128 + k] = (__bf16)(r1 * Wr1[k * DD + n]);
    }
    ba[n] = r0 * bl0[n] + r2 * bl2[n];
    bb[n] = r1 * bl1[n];
    if (n < 3) rw_out[n] = (n == 0 ? r0 : (n == 1 ? r1 : r2));
}

// ---- fill: bucket[d][slot]=src (cap slots); cnt[d]=true degree; overflow list ----
__global__ __launch_bounds__(256) void fill_bucket(const int* __restrict__ src, const int* __restrict__ dst,
                                                   int E, int Nd, int Ns, int cap,
                                                   int* __restrict__ cnt, int* __restrict__ bucket,
                                                   int* __restrict__ ovf_cnt, int2* __restrict__ ovf) {
    int e = blockIdx.x * 256 + threadIdx.x;
    if (e >= E) return;
    int d = dst[e];
    if (d < 0 || d >= Nd) return;
    int s = src[e];
    if (s < 0 || s >= Ns) return;
    int slot = atomicAdd(&cnt[d], 1);
    if (slot < cap) bucket[(size_t)d * cap + slot] = s;
    else { int o = atomicAdd(ovf_cnt, 1); if (o < OVFC) ovf[o] = make_int2(d, s); }
}

// ---- fused gather + MFMA GEMM: one wave per 16-row output tile ----
// KSRC=3 (out_a): A = [mean0 | x_a_row | mean2], K=384
// KSRC=2 (out_b): A = [mean1 | x_b_row],         K=256
template <int KSRC>
__global__ __launch_bounds__(64) void fused_tile(const float* __restrict__ XA,   // gather src for mean0/1
                                                 const float* __restrict__ XB,   // gather src for mean2
                                                 const float* __restrict__ XR,   // right-term x
                                                 const int* __restrict__ C0, const int* __restrict__ BK0, int cap0,
                                                 const int* __restrict__ C2, const int* __restrict__ BK2, int cap2,
                                                 const __bf16* __restrict__ Wt,
                                                 const float* __restrict__ bias,
                                                 float* __restrict__ out, int Nrows) {
    constexpr int K = KSRC * 128;
    constexpr int KP = K + 8;                     // pad: 2-way-free LDS banks, 16B-aligned frags
    __shared__ __bf16 A[16 * KP];
    const int lane = threadIdx.x;
    const int t = blockIdx.x;
    const int c2 = lane * 2;

    // ---- phase 1: cooperative gather (512B-coalesced float2 per lane) ----
    for (int r = 0; r < 16; r++) {
        const int row = t * 16 + r;
        if (row >= Nrows) {
            A[r * KP + c2] = (__bf16)0.f; A[r * KP + c2 + 1] = (__bf16)0.f;
            A[r * KP + 128 + c2] = (__bf16)0.f; A[r * KP + 128 + c2 + 1] = (__bf16)0.f;
            if (KSRC == 3) { A[r * KP + 256 + c2] = (__bf16)0.f; A[r * KP + 256 + c2 + 1] = (__bf16)0.f; }
            continue;
        }
        {   // mean0/1
            const int d = C0[row];
            const int du = d < cap0 ? d : cap0;
            const float sc = 1.0f / fmaxf((float)d, 1.0f);
            const int* bk = BK0 + (size_t)row * cap0;
            float ax = 0.f, ay = 0.f;
            for (int i = 0; i < du; i++) {
                const float2 v = ((const float2*)(XA + (size_t)bk[i] * DD))[lane];
                ax += v.x; ay += v.y;
            }
            A[r * KP + c2] = (__bf16)(ax * sc);
            A[r * KP + c2 + 1] = (__bf16)(ay * sc);
        }
        {   // x row
            const float2 v = ((const float2*)(XR + (size_t)row * DD))[lane];
            A[r * KP + 128 + c2] = (__bf16)v.x;
            A[r * KP + 128 + c2 + 1] = (__bf16)v.y;
        }
        if (KSRC == 3) {   // mean2
            const int d = C2[row];
            const int du = d < cap2 ? d : cap2;
            const float sc = 1.0f / fmaxf((float)d, 1.0f);
            const int* bk = BK2 + (size_t)row * cap2;
            float ax = 0.f, ay = 0.f;
            for (int i = 0; i < du; i++) {
                const float2 v = ((const float2*)(XB + (size_t)bk[i] * DD))[lane];
                ax += v.x; ay += v.y;
            }
            A[r * KP + 256 + c2] = (__bf16)(ax * sc);
            A[r * KP + 256 + c2 + 1] = (__bf16)(ay * sc);
        }
    }
    __syncthreads();

    // ---- phase 2: MFMA (A from LDS, B from global/L2) ----
    const int m = lane & 15;
    const int g = lane >> 4;
    f32x4 acc[8];
#pragma unroll
    for (int n = 0; n < 8; n++) acc[n] = (f32x4)0.0f;
#pragma unroll
    for (int ks = 0; ks < K / 32; ks++) {
        const int koff = ks * 32 + g * 8;
        const bf16x8 a = *(const bf16x8*)(&A[m * KP + koff]);
#pragma unroll
        for (int n = 0; n < 8; n++) {
            const bf16x8 b = *(const bf16x8*)(Wt + (size_t)(n * 16 + m) * K + koff);
            acc[n] = __builtin_amdgcn_mfma_f32_16x16x32_bf16(a, b, acc[n], 0, 0, 0);
        }
    }

    // ---- phase 3: f32 store + bias ----
#pragma unroll
    for (int n = 0; n < 8; n++) {
        const int col = n * 16 + m;
        const float bv = bias[col];
#pragma unroll
        for (int r = 0; r < 4; r++) {
            const int orow = t * 16 + g * 4 + r;
            if (orow < Nrows) out[(size_t)orow * DD + col] = acc[n][r] + bv;
        }
    }
}

// ---- exact overflow correction: out[d] += (x[s] @ Wsec) / deg  (rare) ----
__global__ __launch_bounds__(128) void ovf_fix(const int* __restrict__ ovfc, const int2* __restrict__ ovf,
                                               const float* __restrict__ x, const int* __restrict__ cnt,
                                               const __bf16* __restrict__ Wt, int K, int sec,
                                               float* __restrict__ out) {
    int m = *ovfc;
    if (m > OVFC) m = OVFC;
    const int n = threadIdx.x;
    for (int i = blockIdx.x; i < m; i += gridDim.x) {
        const int2 p = ovf[i];
        const float sc = 1.0f / fmaxf((float)cnt[p.x], 1.0f);
        float acc = 0.f;
        for (int k = 0; k < DD; k++)
            acc += x[(size_t)p.y * DD + k] * (float)Wt[(size_t)n * K + sec + k];
        atomicAdd(&out[(size_t)p.x * DD + n], acc * sc);
    }
}

static inline int imin(int a, int b) { return a < b ? a : b; }

extern "C" void kernel_launch(void* const* d_in, const int* in_sizes, int n_in,
                              void* d_out, int out_size, void* d_ws, size_t ws_size,
                              hipStream_t stream) {
    if (n_in != 18) return;

    const float* x_a = (const float*)d_in[0];
    const float* x_b = (const float*)d_in[1];
    const int* e0_src = (const int*)d_in[2];
    const int* e0_dst = (const int*)d_in[3];
    const int* e1_src = (const int*)d_in[4];
    const int* e1_dst = (const int*)d_in[5];
    const int* e2_src = (const int*)d_in[6];
    const int* e2_dst = (const int*)d_in[7];
    const float* Wl0 = (const float*)d_in[8];
    const float* bl0 = (const float*)d_in[9];
    const float* Wr0 = (const float*)d_in[10];
    const float* Wl1 = (const float*)d_in[11];
    const float* bl1 = (const float*)d_in[12];
    const float* Wr1 = (const float*)d_in[13];
    const float* Wl2 = (const float*)d_in[14];
    const float* bl2 = (const float*)d_in[15];
    const float* Wr2 = (const float*)d_in[16];
    const float* rl  = (const float*)d_in[17];

    const int Na = in_sizes[0] / DD;   // 200000
    const int Nb = in_sizes[1] / DD;   // 100000
    const int E0 = in_sizes[2], E1 = in_sizes[4], E2 = in_sizes[6];

    float* out_f = (float*)d_out;
    float* out_a = out_f;
    float* out_b = out_f + (size_t)Na * DD;
    float* rw_out = out_f + (size_t)Na * DD + (size_t)Nb * DD;

    char* base = (char*)d_ws;
    size_t off = 0;
    auto alloc = [&](size_t bytes) { char* r = base + off; off += (bytes + 511) & ~(size_t)511; return r; };
    int* cnt0 = (int*)alloc((size_t)Na * 4);
    int* cnt1 = (int*)alloc((size_t)Nb * 4);
    int* cnt2 = (int*)alloc((size_t)Na * 4);
    int* ovfc = (int*)alloc(512);                            // [0],[1],[2]
    int2* ovf0 = (int2*)alloc(OVFC * 8);
    int2* ovf1 = (int2*)alloc(OVFC * 8);
    int2* ovf2 = (int2*)alloc(OVFC * 8);
    size_t zero_hi = off;
    __bf16* WtA = (__bf16*)alloc(128 * 384 * 2);
    __bf16* Wtb = (__bf16*)alloc(128 * 256 * 2);
    float* ba = (float*)alloc(512);
    float* bb = (float*)alloc(512);
    // bucket region: bucket0 [Na*CAP02], bucket2 [Na*CAP02]; bucket1 (Nb*CAP1) aliases bucket0 space
    size_t b0cap = (size_t)Na * CAP02;
    size_t b1cap = (size_t)Nb * CAP1;
    int* bucket0 = (int*)alloc((b0cap > b1cap ? b0cap : b1cap) * 4);
    int* bucket2 = (int*)alloc((size_t)Na * CAP02 * 4);
    int* bucket1 = bucket0;                                  // reused after out_b completes
    if (ws_size < off) return;                               // proven >= 28.9MB (R24 bigws ran)

    hipMemsetAsync(d_ws, 0, zero_hi, stream);
    prep_kernel<<<1, 128, 0, stream>>>(Wl0, bl0, Wr0, Wl1, bl1, Wr1, Wl2, bl2, Wr2, rl,
                                       WtA, Wtb, ba, bb, rw_out);

    const int fb0 = (E0 + 255) / 256, fb1 = (E1 + 255) / 256, fb2 = (E2 + 255) / 256;

    // ---- out_b: relation 1 (a -> b) ----
    fill_bucket<<<fb1, 256, 0, stream>>>(e1_src, e1_dst, E1, Nb, Na, CAP1, cnt1, bucket1, ovfc + 1, ovf1);
    fused_tile<2><<<(Nb + 15) / 16, 64, 0, stream>>>(x_a, nullptr, x_b,
                                                     cnt1, bucket1, CAP1,
                                                     nullptr, nullptr, 0,
                                                     Wtb, bb, out_b, Nb);
    ovf_fix<<<32, 128, 0, stream>>>(ovfc + 1, ovf1, x_a, cnt1, Wtb, 256, 0, out_b);

    // ---- out_a: relations 0 (a->a) + 2 (b->a) ----
    fill_bucket<<<fb0, 256, 0, stream>>>(e0_src, e0_dst, E0, Na, Na, CAP02, cnt0, bucket0, ovfc + 0, ovf0);
    fill_bucket<<<fb2, 256, 0, stream>>>(e2_src, e2_dst, E2, Na, Nb, CAP02, cnt2, bucket2, ovfc + 2, ovf2);
    fused_tile<3><<<(Na + 15) / 16, 64, 0, stream>>>(x_a, x_b, x_a,
                                                     cnt0, bucket0, CAP02,
                                                     cnt2, bucket2, CAP02,
                                                     WtA, ba, out_a, Na);
    ovf_fix<<<32, 128, 0, stream>>>(ovfc + 0, ovf0, x_a, cnt0, WtA, 384, 0, out_a);
    ovf_fix<<<32, 128, 0, stream>>>(ovfc + 2, ovf2, x_b, cnt2, WtA, 384, 256, out_a);
}